// Round 7
// baseline (111.492 us; speedup 1.0000x reference)
//
#include <hip/hip_runtime.h>
#include <hip/hip_bf16.h>

#define N     8192
#define FIN   256
#define FOUT  64
#define ALPHA 0.2f
#define KQ    8               // j-split across blocks
#define JQ    (N / KQ)        // 1024 j per block
#define JW    (JQ / 4)        // 256 j per wave
#define NS    (JW / 32)       // 8 MFMA K-steps per wave

typedef __attribute__((ext_vector_type(8))) short bf16x8;
typedef __attribute__((ext_vector_type(4))) float f32x4;
typedef __attribute__((ext_vector_type(4))) int   i32x4;

static __device__ __forceinline__ unsigned short f2bf(float x) {
    union { float f; unsigned int u; } v; v.f = x;
    unsigned int r = v.u + 0x7FFFu + ((v.u >> 16) & 1u);   // RNE
    return (unsigned short)(r >> 16);
}
static __device__ __forceinline__ float asf(unsigned int u) {
    union { unsigned int u; float f; } v; v.u = u; return v.f;
}
// masked exp(leaky_relu(f1+f2)); scores bounded (~15) -> no softmax shift needed
static __device__ __forceinline__ float wcalc(float f1v, float f2v, int a) {
    const float e = f1v + f2v;
    const float lr = fmaxf(e, ALPHA * e);       // leaky relu as max
    const float w = __expf(lr);
    return (a > 0) ? w : 0.f;
}

// ---- kernel 1: h = X@W -> hb[j/8][col][8] (MFMA B-frag layout), f1, f2 ----
__global__ __launch_bounds__(256) void k_h(
        const float* __restrict__ X, const float* __restrict__ W,
        const float* __restrict__ a1, const float* __restrict__ a2,
        unsigned short* __restrict__ hb,
        float* __restrict__ f1, float* __restrict__ f2) {
    const int lane = threadIdx.x & 63;              // = output column
    const int wave = threadIdx.x >> 6;
    const int row0 = (blockIdx.x * 4 + wave) * 4;   // 4 node-rows per wave

    const float4* Xr[4];
    #pragma unroll
    for (int r = 0; r < 4; ++r)
        Xr[r] = (const float4*)(X + (size_t)(row0 + r) * FIN);

    float acc[4] = {0.f, 0.f, 0.f, 0.f};
    #pragma unroll 4
    for (int k4 = 0; k4 < FIN / 4; ++k4) {
        const float w0 = W[(k4 * 4 + 0) * FOUT + lane];
        const float w1 = W[(k4 * 4 + 1) * FOUT + lane];
        const float w2 = W[(k4 * 4 + 2) * FOUT + lane];
        const float w3 = W[(k4 * 4 + 3) * FOUT + lane];
        #pragma unroll
        for (int r = 0; r < 4; ++r) {
            const float4 xv = Xr[r][k4];
            acc[r] = fmaf(xv.x, w0, acc[r]);
            acc[r] = fmaf(xv.y, w1, acc[r]);
            acc[r] = fmaf(xv.z, w2, acc[r]);
            acc[r] = fmaf(xv.w, w3, acc[r]);
        }
    }

    // hb[chunk=row0>>3][col=lane][e=(row0&7)+r], rows row0..row0+3 same chunk
    ushort4 hv;
    hv.x = f2bf(acc[0]); hv.y = f2bf(acc[1]);
    hv.z = f2bf(acc[2]); hv.w = f2bf(acc[3]);
    *(ushort4*)&hb[(size_t)(row0 >> 3) * 512 + lane * 8 + (row0 & 7)] = hv;

    const float a1v = a1[lane];
    const float a2v = a2[lane];
    #pragma unroll
    for (int r = 0; r < 4; ++r) {
        float p1 = acc[r] * a1v;
        float p2 = acc[r] * a2v;
        #pragma unroll
        for (int off = 32; off > 0; off >>= 1) {
            p1 += __shfl_down(p1, off);
            p2 += __shfl_down(p2, off);
        }
        if (lane == 0) { f1[row0 + r] = p1; f2[row0 + r] = p2; }
    }
}

// -------- kernel 2: barrier-free MFMA attention partial sums --------
// block b: row-group b>>3 (16 rows), j-octant b&7; wave owns 256 j (8 K-steps).
// ALL adj loads for the wave issue in the prologue (16 x dwordx4 per lane,
// 64 VGPRs) -> streaming-depth memory pipeline; loop only consumes registers.
__global__ __launch_bounds__(256, 4) void k_attn(
        const int* __restrict__ adj, const unsigned short* __restrict__ hb,
        const float* __restrict__ f1, const float* __restrict__ f2,
        float* __restrict__ part, float* __restrict__ pden) {
    __shared__ f32x4 red[2][256];    // 8 KB epilogue acc staging
    __shared__ float dred[4][16];

    const int t    = threadIdx.x;
    const int lane = t & 63;
    const int wv   = t >> 6;
    const int bid  = blockIdx.x;
    const int rg   = bid >> 3;
    const int q    = bid & 7;
    const int i0   = rg * 16;
    const int r    = lane & 15;     // A-row / B-col-sub / output col
    const int kg   = lane >> 4;     // k-group within K-step

    const float f1v = f1[i0 + r];
    const int jw = q * JQ + wv * JW;
    const int* aptr = adj + (size_t)(i0 + r) * N + jw + kg * 8;
    const float* f2p = f2 + jw + kg * 8;
    const unsigned short* hbp = hb + (size_t)(jw >> 3) * 512 + kg * 512 + r * 8;

    // ---- prologue: the wave's ENTIRE adj window, 16 independent loads ----
    i32x4 am[2 * NS];
    #pragma unroll
    for (int s = 0; s < NS; ++s) {
        am[2 * s]     = *(const i32x4*)(aptr + s * 32);
        am[2 * s + 1] = *(const i32x4*)(aptr + s * 32 + 4);
    }

    f32x4 acc[4];
    #pragma unroll
    for (int c = 0; c < 4; ++c) acc[c] = (f32x4){0.f, 0.f, 0.f, 0.f};
    float sacc = 0.f;

    #pragma unroll
    for (int s = 0; s < NS; ++s) {
        // B-fragments: coalesced 16B loads (hb is MFMA-native layout, L2-hot)
        const unsigned short* hs = hbp + s * 2048;
        const bf16x8 b0 = *(const bf16x8*)(hs);
        const bf16x8 b1 = *(const bf16x8*)(hs + 128);
        const bf16x8 b2 = *(const bf16x8*)(hs + 256);
        const bf16x8 b3 = *(const bf16x8*)(hs + 384);

        const float4 fa = *(const float4*)(f2p + s * 32);
        const float4 fb = *(const float4*)(f2p + s * 32 + 4);
        const i32x4 a0 = am[2 * s];
        const i32x4 a1 = am[2 * s + 1];

        const float w0 = wcalc(f1v, fa.x, a0.x);
        const float w1 = wcalc(f1v, fa.y, a0.y);
        const float w2 = wcalc(f1v, fa.z, a0.z);
        const float w3 = wcalc(f1v, fa.w, a0.w);
        const float w4 = wcalc(f1v, fb.x, a1.x);
        const float w5 = wcalc(f1v, fb.y, a1.y);
        const float w6 = wcalc(f1v, fb.z, a1.z);
        const float w7 = wcalc(f1v, fb.w, a1.w);

        // pack to bf16 pairs (v_cvt_pk_bf16_f32) and build A-frag
        union { bf16x8 v; __hip_bfloat162 h2[4]; unsigned int u[4]; } af;
        af.h2[0] = __float22bfloat162_rn(make_float2(w0, w1));
        af.h2[1] = __float22bfloat162_rn(make_float2(w2, w3));
        af.h2[2] = __float22bfloat162_rn(make_float2(w4, w5));
        af.h2[3] = __float22bfloat162_rn(make_float2(w6, w7));

        // denominator from the ROUNDED weights (bit-extract from packed pairs)
        float ds = 0.f;
        #pragma unroll
        for (int u = 0; u < 4; ++u)
            ds += asf(af.u[u] << 16) + asf(af.u[u] & 0xFFFF0000u);
        sacc += ds;

        acc[0] = __builtin_amdgcn_mfma_f32_16x16x32_bf16(af.v, b0, acc[0], 0, 0, 0);
        acc[1] = __builtin_amdgcn_mfma_f32_16x16x32_bf16(af.v, b1, acc[1], 0, 0, 0);
        acc[2] = __builtin_amdgcn_mfma_f32_16x16x32_bf16(af.v, b2, acc[2], 0, 0, 0);
        acc[3] = __builtin_amdgcn_mfma_f32_16x16x32_bf16(af.v, b3, acc[3], 0, 0, 0);
    }

    // ---- denominator: lanes l, l+16, l+32, l+48 share a row ----
    sacc += __shfl_xor(sacc, 16);
    sacc += __shfl_xor(sacc, 32);
    if (lane < 16) dred[wv][lane] = sacc;

    // ---- acc tree-reduce across the 4 waves ----
    __syncthreads();
    if (wv >= 2) {
        #pragma unroll
        for (int cg = 0; cg < 4; ++cg) red[wv - 2][lane * 4 + cg] = acc[cg];
    }
    __syncthreads();
    if (wv < 2) {
        #pragma unroll
        for (int cg = 0; cg < 4; ++cg) acc[cg] += red[wv][lane * 4 + cg];
    }
    __syncthreads();
    if (wv == 1) {
        #pragma unroll
        for (int cg = 0; cg < 4; ++cg) red[0][lane * 4 + cg] = acc[cg];
    }
    __syncthreads();
    if (wv == 0) {
        #pragma unroll
        for (int cg = 0; cg < 4; ++cg) acc[cg] += red[0][lane * 4 + cg];
        // C/D layout: col = cg*16 + (lane&15), row = (lane>>4)*4 + reg
        #pragma unroll
        for (int cg = 0; cg < 4; ++cg)
            #pragma unroll
            for (int rr = 0; rr < 4; ++rr)
                part[(size_t)bid * 1024 + (kg * 4 + rr) * FOUT + cg * 16 + r]
                    = acc[cg][rr];
        if (lane < 16)
            pden[bid * 16 + lane] =
                dred[0][lane] + dred[1][lane] + dred[2][lane] + dred[3][lane];
    }
}

// -------- kernel 3: combine KQ partials, normalize, ELU --------
__global__ __launch_bounds__(256) void k_fin(
        const float* __restrict__ part, const float* __restrict__ pden,
        float* __restrict__ out) {
    const int rg = blockIdx.x;
    const int t  = threadIdx.x;
    const int r  = t >> 4;
    const int c4 = (t & 15) * 4;

    float4 v = make_float4(0.f, 0.f, 0.f, 0.f);
    float den = 0.f;
    #pragma unroll
    for (int p = 0; p < KQ; ++p) {
        const int blk = rg * KQ + p;
        const float4 pv = *(const float4*)
            &part[(size_t)blk * 1024 + r * FOUT + c4];
        v.x += pv.x; v.y += pv.y; v.z += pv.z; v.w += pv.w;
        den += pden[blk * 16 + r];
    }
    den = fmaxf(den, 1e-30f);
    const float inv = __fdividef(1.f, den);
    float4 o;
    const float h0 = v.x * inv; o.x = (h0 > 0.f) ? h0 : (__expf(h0) - 1.f);
    const float h1 = v.y * inv; o.y = (h1 > 0.f) ? h1 : (__expf(h1) - 1.f);
    const float h2 = v.z * inv; o.z = (h2 > 0.f) ? h2 : (__expf(h2) - 1.f);
    const float h3 = v.w * inv; o.w = (h3 > 0.f) ? h3 : (__expf(h3) - 1.f);
    *(float4*)&out[(size_t)(rg * 16 + r) * FOUT + c4] = o;
}

extern "C" void kernel_launch(void* const* d_in, const int* in_sizes, int n_in,
                              void* d_out, int out_size, void* d_ws, size_t ws_size,
                              hipStream_t stream) {
    const float* X   = (const float*)d_in[0];
    const int*   adj = (const int*)d_in[1];
    const float* W   = (const float*)d_in[2];
    const float* a1  = (const float*)d_in[3];
    const float* a2  = (const float*)d_in[4];
    float* out = (float*)d_out;

    unsigned short* hb = (unsigned short*)d_ws;                   // 1 MB
    float* f1   = (float*)((char*)d_ws + (size_t)FOUT * N * 2);   // N floats
    float* f2   = f1 + N;                                         // N floats
    float* part = f2 + N;                                         // 4096*1024 floats
    float* pden = part + (size_t)(N / 16) * KQ * 1024;            // 4096*16 floats

    k_h   <<<N / 16, 256, 0, stream>>>(X, W, a1, a2, hb, f1, f2);
    k_attn<<<(N / 16) * KQ, 256, 0, stream>>>(adj, hb, f1, f2, part, pden);
    k_fin <<<N / 16, 256, 0, stream>>>(part, pden, out);
}